// Round 7
// baseline (698.598 us; speedup 1.0000x reference)
//
#include <hip/hip_runtime.h>
#include <math.h>

// ---------------------------------------------------------------------------
// ChebNet: 3x ChebConv(S=7) + ReLU, then FC(64->1).
// N=50000 nodes, E=800000 edges, F_IN=16, H=64.
// R5/R6: (a) bucketed 2-phase CSR build (64-row buckets == contiguous CSR
// regions; append staging + LDS-cursor finalize -> coalesced cw writes,
// kills the 17x write amplification), (b) feature-sliced SpMV on dense
// [N][32] fp16 slice buffers (3.2 MB gather set fits 4 MB per-XCD L2),
// nontemporal streams for cw/sub/xout so L2 keeps only the gather set.
// (R6 fix: nontemporal builtins via u64 union, not HIP_vector_type.)
// ---------------------------------------------------------------------------

#define WS_ALIGN(x) (((size_t)(x) + 255) & ~(size_t)255)

using f16x8 = __attribute__((ext_vector_type(8))) _Float16;
using f32x4 = __attribute__((ext_vector_type(4))) float;

__device__ inline float h2f_bits(unsigned int b) {
  unsigned short s = (unsigned short)(b & 0xffffu);
  _Float16 h;
  __builtin_memcpy(&h, &s, 2);
  return (float)h;
}
__device__ inline unsigned short f2h_bits(float f) {
  _Float16 h = (_Float16)f;
  unsigned short s;
  __builtin_memcpy(&s, &h, 2);
  return s;
}
union H4 {
  ushort4 u;
  _Float16 h[4];
  unsigned long long q;
};

__global__ __launch_bounds__(256) void hist_kernel(const int* __restrict__ row, int E,
                                                   int* __restrict__ deg) {
  int i = blockIdx.x * 256 + threadIdx.x;
  if (i < E) atomicAdd(&deg[row[i]], 1);
}

// ---- hierarchical scan ----
__global__ __launch_bounds__(256) void scan_sum_kernel(const int* __restrict__ deg,
                                                       int* __restrict__ bsum, int n) {
  int base = blockIdx.x * 1024 + threadIdx.x;
  int v = 0;
#pragma unroll
  for (int u = 0; u < 4; ++u) {
    int i = base + u * 256;
    if (i < n) v += deg[i];
  }
#pragma unroll
  for (int off = 32; off > 0; off >>= 1) v += __shfl_down(v, off, 64);
  __shared__ int ws[4];
  int lane = threadIdx.x & 63, wave = threadIdx.x >> 6;
  if (lane == 0) ws[wave] = v;
  __syncthreads();
  if (threadIdx.x == 0) bsum[blockIdx.x] = ws[0] + ws[1] + ws[2] + ws[3];
}

__global__ __launch_bounds__(64) void scan_bsum_kernel(int* __restrict__ bsum, int nb) {
  int t = threadIdx.x;
  int v = (t < nb) ? bsum[t] : 0;
  int sc = v;
#pragma unroll
  for (int off = 1; off < 64; off <<= 1) {
    int tv = __shfl_up(sc, off, 64);
    if (t >= off) sc += tv;
  }
  if (t < nb) bsum[t] = sc - v;
}

__global__ __launch_bounds__(256) void scan_out_kernel(const int* __restrict__ deg,
                                                       const int* __restrict__ bsum,
                                                       int* __restrict__ row_ptr,
                                                       float* __restrict__ dis, int n) {
  int base = blockIdx.x * 1024 + threadIdx.x * 4;
  int loc[4];
  int s = 0;
#pragma unroll
  for (int u = 0; u < 4; ++u) {
    int i = base + u;
    loc[u] = (i < n) ? deg[i] : 0;
    s += loc[u];
  }
  int lane = threadIdx.x & 63, wave = threadIdx.x >> 6;
  int sc = s;
#pragma unroll
  for (int off = 1; off < 64; off <<= 1) {
    int tv = __shfl_up(sc, off, 64);
    if (lane >= off) sc += tv;
  }
  __shared__ int wtot[4];
  if (lane == 63) wtot[wave] = sc;
  __syncthreads();
  int pre = sc - s + bsum[blockIdx.x];
  for (int w = 0; w < wave; ++w) pre += wtot[w];
  if (blockIdx.x == 0 && threadIdx.x == 0) row_ptr[0] = 0;
  int running = pre;
#pragma unroll
  for (int u = 0; u < 4; ++u) {
    int i = base + u;
    if (i < n) {
      dis[i] = (loc[u] > 0) ? (1.0f / sqrtf((float)loc[u])) : 0.0f;
      running += loc[u];
      row_ptr[i + 1] = running;
    }
  }
}

// bucket cursors: bucket b = rows [64b, 64b+64), region starts at row_ptr[64b]
__global__ __launch_bounds__(256) void bcur_init_kernel(const int* __restrict__ row_ptr,
                                                        int* __restrict__ bcur, int nb) {
  int b = blockIdx.x * 256 + threadIdx.x;
  if (b < nb) bcur[b] = row_ptr[b * 64];
}

// Phase C: append (r<<16|c) into the bucket's CSR region (mostly-sequential).
__global__ __launch_bounds__(256) void scatter_rc_kernel(const int* __restrict__ row,
                                                         const int* __restrict__ col, int E,
                                                         int* __restrict__ bcur,
                                                         unsigned int* __restrict__ rc_stage) {
  int i = blockIdx.x * 256 + threadIdx.x;
  if (i >= E) return;
  int r = row[i], c = col[i];
  int pos = atomicAdd(&bcur[r >> 6], 1);
  rc_stage[pos] = ((unsigned int)r << 16) | (unsigned int)c;
}

// Phase D: one block per bucket; exact CSR placement via LDS cursors,
// LDS-staged cw, coalesced stream-out.  cw entry: (col<<16)|fp16(w).
__global__ __launch_bounds__(256) void bucket_finalize_kernel(
    const int* __restrict__ row_ptr, const unsigned int* __restrict__ rc_stage,
    const float* __restrict__ dis, const float* __restrict__ lamp,
    unsigned int* __restrict__ cw, int n) {
  __shared__ int lcur[64];
  __shared__ unsigned int lcw[4096];
  int r0 = blockIdx.x * 64;
  int r1 = min(r0 + 64, n);
  int base = row_ptr[r0];
  int cnt = row_ptr[r1] - base;
  int t = threadIdx.x;
  if (t < r1 - r0) lcur[t] = row_ptr[r0 + t] - base;
  __syncthreads();
  float sc = -(2.0f / lamp[0]);
  bool fits = (cnt <= 4096);
  for (int j = t; j < cnt; j += 256) {
    unsigned int e = rc_stage[base + j];
    int r = (int)(e >> 16), c = (int)(e & 0xffffu);
    float w = sc * dis[r] * dis[c];
    unsigned int val = ((unsigned int)c << 16) | (unsigned int)f2h_bits(w);
    int p = atomicAdd(&lcur[r - r0], 1);
    if (fits)
      lcw[p] = val;
    else
      cw[base + p] = val;
  }
  __syncthreads();
  if (fits)
    for (int j = t; j < cnt; j += 256) cw[base + j] = lcw[j];
}

// x (N x 16 fp32) -> T1 slot0 fp16 dense [N][16]; zero pad slot 7.
__global__ __launch_bounds__(256) void x_to_slots_kernel(const float* __restrict__ x,
                                                         ushort* __restrict__ T1, int n) {
  int t = blockIdx.x * 256 + threadIdx.x;
  if (t < n * 4) {
    int row = t >> 2, q = t & 3;
    float4 v = ((const float4*)x)[(size_t)row * 4 + q];
    ushort4 o;
    o.x = f2h_bits(v.x);
    o.y = f2h_bits(v.y);
    o.z = f2h_bits(v.z);
    o.w = f2h_bits(v.w);
    ((ushort4*)T1)[(size_t)row * 4 + q] = o;
  } else if (t < n * 8) {
    int t2 = t - n * 4;
    ((ushort4*)(T1 + (size_t)7 * n * 16))[t2] = make_ushort4(0, 0, 0, 0);
  }
}

// Pack W ([KREAL][64] f32, zero-padded to KT*32) into MFMA B-fragment order.
template <int KREAL, int KT>
__global__ __launch_bounds__(256) void wpk_prep(const float* __restrict__ W,
                                                ushort* __restrict__ Wpk) {
  int t = blockIdx.x * 256 + threadIdx.x;
  if (t >= KT * 256) return;
  int kt = t >> 8, nt = (t >> 6) & 3, l = t & 63;
  int col = nt * 16 + (l & 15);
  int kb = kt * 32 + ((l >> 4) << 3);
  ushort tmp[8];
#pragma unroll
  for (int j = 0; j < 8; ++j) {
    int k = kb + j;
    float v = (k < KREAL) ? W[(size_t)k * 64 + col] : 0.0f;
    tmp[j] = f2h_bits(v);
  }
  ushort4* dst = (ushort4*)Wpk + (size_t)((kt * 4 + nt) * 64 + l) * 2;
  dst[0] = make_ushort4(tmp[0], tmp[1], tmp[2], tmp[3]);
  dst[1] = make_ushort4(tmp[4], tmp[5], tmp[6], tmp[7]);
}

// ---------------------------------------------------------------------------
// Feature-sliced SpMV on dense [N][SW] fp16 buffers (SW = 16 or 32).
// MODE 0: out = spmv(xin);  MODE 1: out = 2*spmv(xin) - sub.
// cw/sub nontemporal-read, xout nontemporal-written: L2 keeps the gather set.
// ---------------------------------------------------------------------------
template <int SW, int MODE>
__global__ __launch_bounds__(256) void spmv_slice(const int* __restrict__ row_ptr,
                                                  const unsigned int* __restrict__ cw,
                                                  const float* __restrict__ lamp,
                                                  const ushort4* __restrict__ xin,
                                                  const ushort4* __restrict__ sub,
                                                  ushort4* __restrict__ xout, int n) {
  constexpr int LPR = SW / 4;     // lanes per row
  constexpr int RPB = 256 / LPR;  // rows per block
  constexpr int EPL = 16 / LPR;   // cw entries per lane per 16-edge batch
  int i = blockIdx.x * RPB + threadIdx.y;
  if (i >= n) return;
  int f4 = threadIdx.x;
  int lane = (threadIdx.y * LPR + f4) & 63;
  int grpbase = lane - f4;
  float diag = 2.0f / lamp[0] - 1.0f;
  H4 xd;
  xd.u = xin[(size_t)i * LPR + f4];
  float4 a = make_float4(diag * (float)xd.h[0], diag * (float)xd.h[1],
                         diag * (float)xd.h[2], diag * (float)xd.h[3]);
  int s = row_ptr[i], e = row_ptr[i + 1];

  for (int j0 = s; j0 < e; j0 += 16) {
    unsigned int pv[EPL];
#pragma unroll
    for (int u = 0; u < EPL; ++u) {
      int jj = j0 + f4 * EPL + u;
      pv[u] = __builtin_nontemporal_load(&cw[jj < e ? jj : (e - 1)]);
    }
    H4 xv[16];
    float ww[16];
#pragma unroll
    for (int u = 0; u < 16; ++u) {
      unsigned int pu = (unsigned int)__shfl((int)pv[u % EPL], grpbase + u / EPL, 64);
      bool valid = (j0 + u) < e;
      ww[u] = valid ? h2f_bits(pu) : 0.0f;
      int ad = valid ? (int)(pu >> 16) : i;
      xv[u].u = xin[(size_t)ad * LPR + f4];
    }
#pragma unroll
    for (int u = 0; u < 16; ++u) {
      a.x += ww[u] * (float)xv[u].h[0];
      a.y += ww[u] * (float)xv[u].h[1];
      a.z += ww[u] * (float)xv[u].h[2];
      a.w += ww[u] * (float)xv[u].h[3];
    }
  }

  float4 r;
  if (MODE == 1) {
    H4 sv;
    sv.q = __builtin_nontemporal_load((const unsigned long long*)&sub[(size_t)i * LPR + f4]);
    r = make_float4(2.0f * a.x - (float)sv.h[0], 2.0f * a.y - (float)sv.h[1],
                    2.0f * a.z - (float)sv.h[2], 2.0f * a.w - (float)sv.h[3]);
  } else {
    r = a;
  }
  H4 o;
  o.u.x = f2h_bits(r.x);
  o.u.y = f2h_bits(r.y);
  o.u.z = f2h_bits(r.z);
  o.u.w = f2h_bits(r.w);
  __builtin_nontemporal_store(o.q, (unsigned long long*)&xout[(size_t)i * LPR + f4]);
}

// ---------------------------------------------------------------------------
// MFMA GEMM over slot-major slices: D[N x 64] = A_cat[N x KT*32] @ Wpk (+bias,
// relu -> fp16 slot0/1 of dst slices) or raw fp32 acc (LAST).
// A slice layout: SW=32: K-tile kt == slot kt, lane k-off=(l>>4)*8.
//                 SW=16: kt spans slots {2kt,2kt+1}: slot=2kt+((l>>4)>>1),
//                 off=((l>>4)&1)*8.
// ---------------------------------------------------------------------------
template <int SW, int KT, bool LAST>
__global__ __launch_bounds__(256) void gemm_mfma(const ushort* __restrict__ A,
                                                 const ushort* __restrict__ Wpk,
                                                 const float* __restrict__ bias,
                                                 ushort* __restrict__ dsth,
                                                 float* __restrict__ dacc, int n) {
  int l = threadIdx.x & 63;
  int tile = blockIdx.x * 4 + (threadIdx.x >> 6);
  int r0 = tile * 16;
  if (r0 >= n) return;
  size_t slotsz = (size_t)n * SW;
  int row = r0 + (l & 15);
  const f16x8* bp = (const f16x8*)Wpk + l;
  f32x4 c[4] = {{0.f, 0.f, 0.f, 0.f},
                {0.f, 0.f, 0.f, 0.f},
                {0.f, 0.f, 0.f, 0.f},
                {0.f, 0.f, 0.f, 0.f}};
#pragma unroll
  for (int kt = 0; kt < KT; ++kt) {
    int slot, off;
    if constexpr (SW == 32) {
      slot = kt;
      off = (l >> 4) << 3;
    } else {
      slot = 2 * kt + ((l >> 4) >> 1);
      off = ((l >> 4) & 1) << 3;
    }
    f16x8 af = *(const f16x8*)(A + slot * slotsz + (size_t)row * SW + off);
#pragma unroll
    for (int nt = 0; nt < 4; ++nt) {
      f16x8 bf = bp[(kt * 4 + nt) * 64];
      c[nt] = __builtin_amdgcn_mfma_f32_16x16x32_f16(af, bf, c[nt], 0, 0, 0);
    }
  }
  int rb = r0 + ((l >> 4) << 2);
  int cc = l & 15;
  size_t dslot = (size_t)n * 32;
#pragma unroll
  for (int nt = 0; nt < 4; ++nt) {
    int col = nt * 16 + cc;
    if (LAST) {
#pragma unroll
      for (int j = 0; j < 4; ++j) dacc[(size_t)(rb + j) * 64 + col] = c[nt][j];
    } else {
      float bv = bias[col];
      ushort* dbase = dsth + (col >> 5) * dslot + (col & 31);
#pragma unroll
      for (int j = 0; j < 4; ++j) {
        float v = fmaxf(c[nt][j] + bv, 0.0f);
        dbase[(size_t)(rb + j) * 32] = f2h_bits(v);
      }
    }
  }
}

// layer-3 epilogue: out[i] = sum_h relu(acc[i,h]+b[h]) * Wfc[h] + bfc
__global__ __launch_bounds__(256) void fc_fused_kernel(const float* __restrict__ acc,
                                                       const float* __restrict__ b,
                                                       const float* __restrict__ Wfc,
                                                       const float* __restrict__ bfc,
                                                       float* __restrict__ out, int n) {
  int i = blockIdx.x * 4 + threadIdx.y;
  if (i >= n) return;
  int l = threadIdx.x;
  float v = fmaxf(acc[(size_t)i * 64 + l] + b[l], 0.0f) * Wfc[l];
#pragma unroll
  for (int off = 32; off > 0; off >>= 1) v += __shfl_down(v, off, 64);
  if (l == 0) out[i] = v + bfc[0];
}

extern "C" void kernel_launch(void* const* d_in, const int* in_sizes, int n_in, void* d_out,
                              int out_size, void* d_ws, size_t ws_size, hipStream_t stream) {
  const float* x = (const float*)d_in[0];
  const int* ei = (const int*)d_in[1];
  const float* lamp = (const float*)d_in[2];
  const float* W1 = (const float*)d_in[3];
  const float* b1 = (const float*)d_in[4];
  const float* W2 = (const float*)d_in[5];
  const float* b2 = (const float*)d_in[6];
  const float* W3 = (const float*)d_in[7];
  const float* b3 = (const float*)d_in[8];
  const float* Wfc = (const float*)d_in[9];
  const float* bfc = (const float*)d_in[10];

  const int N = in_sizes[0] / 16;  // 50000 (< 65536 required for packing)
  const int E = in_sizes[1] / 2;
  const int* row = ei;
  const int* col = ei + E;

  // ---- workspace carve ----
  char* p = (char*)d_ws;
  auto alloc = [&](size_t bytes) {
    char* r = p;
    p += WS_ALIGN(bytes);
    return r;
  };
  int* deg = (int*)alloc((size_t)N * 4);
  int* row_ptr = (int*)alloc((size_t)(N + 1) * 4);
  int* bcur = (int*)alloc((size_t)((N + 63) / 64) * 4);
  unsigned int* cw = (unsigned int*)alloc((size_t)E * 4);
  unsigned int* rc_stage = (unsigned int*)alloc((size_t)E * 4);
  float* dis = (float*)alloc((size_t)N * 4);
  int* bsum = (int*)alloc(256 * 4);
  ushort* T1 = (ushort*)alloc((size_t)8 * N * 16 * 2);    // 8 slots [N][16] (slot7 = pad)
  ushort* TXC = (ushort*)alloc((size_t)14 * N * 32 * 2);  // 14 slots [N][32]
  float* acc = (float*)alloc((size_t)N * 64 * 4);
  ushort* Wpk1 = (ushort*)alloc((size_t)4 * 256 * 8 * 2);
  ushort* Wpk2 = (ushort*)alloc((size_t)14 * 256 * 8 * 2);
  ushort* Wpk3 = (ushort*)alloc((size_t)14 * 256 * 8 * 2);
  (void)ws_size;
  (void)n_in;
  (void)out_size;

  const int NB = (N + 63) / 64;  // buckets of 64 rows

  // ---- CSR build (bucketed, write-coalesced) ----
  (void)hipMemsetAsync(deg, 0, (size_t)N * 4, stream);
  hist_kernel<<<(E + 255) / 256, 256, 0, stream>>>(row, E, deg);
  int nb = (N + 1023) / 1024;
  scan_sum_kernel<<<nb, 256, 0, stream>>>(deg, bsum, N);
  scan_bsum_kernel<<<1, 64, 0, stream>>>(bsum, nb);
  scan_out_kernel<<<nb, 256, 0, stream>>>(deg, bsum, row_ptr, dis, N);
  bcur_init_kernel<<<(NB + 255) / 256, 256, 0, stream>>>(row_ptr, bcur, NB);
  scatter_rc_kernel<<<(E + 255) / 256, 256, 0, stream>>>(row, col, E, bcur, rc_stage);
  bucket_finalize_kernel<<<NB, 256, 0, stream>>>(row_ptr, rc_stage, dis, lamp, cw, N);

  // ---- weight packing + input conversion ----
  x_to_slots_kernel<<<(N * 8 + 255) / 256, 256, 0, stream>>>(x, T1, N);
  wpk_prep<112, 4><<<4, 256, 0, stream>>>(W1, Wpk1);
  wpk_prep<448, 14><<<14, 256, 0, stream>>>(W2, Wpk2);
  wpk_prep<448, 14><<<14, 256, 0, stream>>>(W3, Wpk3);

  // ---- layer 1 (slices = whole 16-wide rows, slots [N][16]) ----
  {
    size_t ssz = (size_t)N * 16;  // ushorts per slot
    auto S = [&](int k) { return (ushort4*)(T1 + (size_t)k * ssz); };
    dim3 bs(4, 64);
    int gs = (N + 63) / 64;
    spmv_slice<16, 0><<<gs, bs, 0, stream>>>(row_ptr, cw, lamp, S(0), nullptr, S(1), N);
    for (int k = 2; k < 7; ++k)
      spmv_slice<16, 1><<<gs, bs, 0, stream>>>(row_ptr, cw, lamp, S(k - 1), S(k - 2), S(k), N);
    gemm_mfma<16, 4, false><<<(N / 16 + 3) / 4 + 1, 256, 0, stream>>>(T1, Wpk1, b1, TXC,
                                                                      nullptr, N);
  }

  // ---- layers 2,3 (two 32-wide slices; slot index = 2k+s) ----
  for (int layer = 2; layer <= 3; ++layer) {
    size_t ssz = (size_t)N * 32;
    auto S = [&](int k, int s) { return (ushort4*)(TXC + (size_t)(2 * k + s) * ssz); };
    dim3 bs(8, 32);
    int gs = (N + 31) / 32;
    for (int s = 0; s < 2; ++s) {
      spmv_slice<32, 0><<<gs, bs, 0, stream>>>(row_ptr, cw, lamp, S(0, s), nullptr, S(1, s),
                                               N);
      for (int k = 2; k < 7; ++k)
        spmv_slice<32, 1><<<gs, bs, 0, stream>>>(row_ptr, cw, lamp, S(k - 1, s), S(k - 2, s),
                                                 S(k, s), N);
    }
    if (layer == 2)
      gemm_mfma<32, 14, false><<<(N / 16 + 3) / 4 + 1, 256, 0, stream>>>(TXC, Wpk2, b2, TXC,
                                                                         nullptr, N);
    else
      gemm_mfma<32, 14, true><<<(N / 16 + 3) / 4 + 1, 256, 0, stream>>>(TXC, Wpk3, nullptr,
                                                                        nullptr, acc, N);
  }

  // ---- fused bias+relu+FC ----
  fc_fused_kernel<<<(N + 3) / 4, dim3(64, 4), 0, stream>>>(acc, b3, Wfc, bfc, (float*)d_out,
                                                           N);
}

// Round 8
// 426.138 us; speedup vs baseline: 1.6394x; 1.6394x over previous
//
#include <hip/hip_runtime.h>
#include <math.h>

// ---------------------------------------------------------------------------
// ChebNet: 3x ChebConv(S=7) + ReLU, then FC(64->1).
// N=50000 nodes, E=800000 edges, F_IN=16, H=64.
// R8: revert CSR scatter to per-row cursors (R4, 43us known-good; bucket
// cursors caused 190us of cross-XCD atomic line bouncing). Remove ALL
// nontemporal hints (they evicted cw + slice buffers from L2 - backwards).
// Keep feature-sliced SpMV (two [N][32] fp16 slices, each < 4MB per-XCD L2);
// both slices fused in one launch, slice = blockIdx.x & 1 (round-robin XCD
// dispatch => each XCD works mostly one slice). MFMA GEMM unchanged.
// ---------------------------------------------------------------------------

#define WS_ALIGN(x) (((size_t)(x) + 255) & ~(size_t)255)

using f16x8 = __attribute__((ext_vector_type(8))) _Float16;
using f32x4 = __attribute__((ext_vector_type(4))) float;

__device__ inline float h2f_bits(unsigned int b) {
  unsigned short s = (unsigned short)(b & 0xffffu);
  _Float16 h;
  __builtin_memcpy(&h, &s, 2);
  return (float)h;
}
__device__ inline unsigned short f2h_bits(float f) {
  _Float16 h = (_Float16)f;
  unsigned short s;
  __builtin_memcpy(&s, &h, 2);
  return s;
}
union H4 {
  ushort4 u;
  _Float16 h[4];
};

__global__ __launch_bounds__(256) void hist_kernel(const int* __restrict__ row, int E,
                                                   int* __restrict__ deg) {
  int i = blockIdx.x * 256 + threadIdx.x;
  if (i < E) atomicAdd(&deg[row[i]], 1);
}

// ---- hierarchical scan ----
__global__ __launch_bounds__(256) void scan_sum_kernel(const int* __restrict__ deg,
                                                       int* __restrict__ bsum, int n) {
  int base = blockIdx.x * 1024 + threadIdx.x;
  int v = 0;
#pragma unroll
  for (int u = 0; u < 4; ++u) {
    int i = base + u * 256;
    if (i < n) v += deg[i];
  }
#pragma unroll
  for (int off = 32; off > 0; off >>= 1) v += __shfl_down(v, off, 64);
  __shared__ int ws[4];
  int lane = threadIdx.x & 63, wave = threadIdx.x >> 6;
  if (lane == 0) ws[wave] = v;
  __syncthreads();
  if (threadIdx.x == 0) bsum[blockIdx.x] = ws[0] + ws[1] + ws[2] + ws[3];
}

__global__ __launch_bounds__(64) void scan_bsum_kernel(int* __restrict__ bsum, int nb) {
  int t = threadIdx.x;
  int v = (t < nb) ? bsum[t] : 0;
  int sc = v;
#pragma unroll
  for (int off = 1; off < 64; off <<= 1) {
    int tv = __shfl_up(sc, off, 64);
    if (t >= off) sc += tv;
  }
  if (t < nb) bsum[t] = sc - v;
}

__global__ __launch_bounds__(256) void scan_out_kernel(const int* __restrict__ deg,
                                                       const int* __restrict__ bsum,
                                                       int* __restrict__ row_ptr,
                                                       int* __restrict__ cursor,
                                                       float* __restrict__ dis, int n) {
  int base = blockIdx.x * 1024 + threadIdx.x * 4;
  int loc[4];
  int s = 0;
#pragma unroll
  for (int u = 0; u < 4; ++u) {
    int i = base + u;
    loc[u] = (i < n) ? deg[i] : 0;
    s += loc[u];
  }
  int lane = threadIdx.x & 63, wave = threadIdx.x >> 6;
  int sc = s;
#pragma unroll
  for (int off = 1; off < 64; off <<= 1) {
    int tv = __shfl_up(sc, off, 64);
    if (lane >= off) sc += tv;
  }
  __shared__ int wtot[4];
  if (lane == 63) wtot[wave] = sc;
  __syncthreads();
  int pre = sc - s + bsum[blockIdx.x];
  for (int w = 0; w < wave; ++w) pre += wtot[w];
  if (blockIdx.x == 0 && threadIdx.x == 0) row_ptr[0] = 0;
  int running = pre;
#pragma unroll
  for (int u = 0; u < 4; ++u) {
    int i = base + u;
    if (i < n) {
      cursor[i] = running;
      dis[i] = (loc[u] > 0) ? (1.0f / sqrtf((float)loc[u])) : 0.0f;
      running += loc[u];
      row_ptr[i + 1] = running;
    }
  }
}

// Per-row cursor scatter (R4): cw entry = (col<<16)|fp16(w).  N < 65536.
__global__ __launch_bounds__(256) void scatter_kernel(const int* __restrict__ row,
                                                      const int* __restrict__ col, int E,
                                                      int* __restrict__ cursor,
                                                      const float* __restrict__ dis,
                                                      const float* __restrict__ lamp,
                                                      unsigned int* __restrict__ cw) {
  int i = blockIdx.x * 256 + threadIdx.x;
  if (i >= E) return;
  int r = row[i], c = col[i];
  int pos = atomicAdd(&cursor[r], 1);
  float w = -(2.0f / lamp[0]) * dis[r] * dis[c];
  cw[pos] = ((unsigned int)c << 16) | (unsigned int)f2h_bits(w);
}

// x (N x 16 fp32) -> T1 slot0 fp16 dense [N][16]; zero pad slot 7.
__global__ __launch_bounds__(256) void x_to_slots_kernel(const float* __restrict__ x,
                                                         ushort* __restrict__ T1, int n) {
  int t = blockIdx.x * 256 + threadIdx.x;
  if (t < n * 4) {
    int row = t >> 2, q = t & 3;
    float4 v = ((const float4*)x)[(size_t)row * 4 + q];
    ushort4 o;
    o.x = f2h_bits(v.x);
    o.y = f2h_bits(v.y);
    o.z = f2h_bits(v.z);
    o.w = f2h_bits(v.w);
    ((ushort4*)T1)[(size_t)row * 4 + q] = o;
  } else if (t < n * 8) {
    int t2 = t - n * 4;
    ((ushort4*)(T1 + (size_t)7 * n * 16))[t2] = make_ushort4(0, 0, 0, 0);
  }
}

// Pack W ([KREAL][64] f32, zero-padded to KT*32) into MFMA B-fragment order.
template <int KREAL, int KT>
__global__ __launch_bounds__(256) void wpk_prep(const float* __restrict__ W,
                                                ushort* __restrict__ Wpk) {
  int t = blockIdx.x * 256 + threadIdx.x;
  if (t >= KT * 256) return;
  int kt = t >> 8, nt = (t >> 6) & 3, l = t & 63;
  int col = nt * 16 + (l & 15);
  int kb = kt * 32 + ((l >> 4) << 3);
  ushort tmp[8];
#pragma unroll
  for (int j = 0; j < 8; ++j) {
    int k = kb + j;
    float v = (k < KREAL) ? W[(size_t)k * 64 + col] : 0.0f;
    tmp[j] = f2h_bits(v);
  }
  ushort4* dst = (ushort4*)Wpk + (size_t)((kt * 4 + nt) * 64 + l) * 2;
  dst[0] = make_ushort4(tmp[0], tmp[1], tmp[2], tmp[3]);
  dst[1] = make_ushort4(tmp[4], tmp[5], tmp[6], tmp[7]);
}

// ---------------------------------------------------------------------------
// Feature-sliced SpMV on dense [N][SW] fp16 buffers (SW = 16 or 32).
// MODE 0: out = spmv(xin);  MODE 1: out = 2*spmv(xin) - sub.
// SLICES=2: two independent slices in one launch, slice = blockIdx.x & 1
// (round-robin XCD dispatch keeps each XCD mostly on one 3.2MB slice).
// ---------------------------------------------------------------------------
template <int SW, int MODE, int SLICES>
__global__ __launch_bounds__(256) void spmv_slice(const int* __restrict__ row_ptr,
                                                  const unsigned int* __restrict__ cw,
                                                  const float* __restrict__ lamp,
                                                  const ushort4* __restrict__ xin,
                                                  const ushort4* __restrict__ sub,
                                                  ushort4* __restrict__ xout, int ssz4,
                                                  int n) {
  constexpr int LPR = SW / 4;     // lanes per row
  constexpr int RPB = 256 / LPR;  // rows per block
  constexpr int EPL = 16 / LPR;   // cw entries per lane per 16-edge batch
  int bx = blockIdx.x;
  if (SLICES == 2) {
    int sl = bx & 1;
    bx >>= 1;
    xin += (size_t)sl * ssz4;
    if (MODE == 1) sub += (size_t)sl * ssz4;
    xout += (size_t)sl * ssz4;
  }
  int i = bx * RPB + threadIdx.y;
  if (i >= n) return;
  int f4 = threadIdx.x;
  int lane = (threadIdx.y * LPR + f4) & 63;
  int grpbase = lane - f4;
  float diag = 2.0f / lamp[0] - 1.0f;
  H4 xd;
  xd.u = xin[(size_t)i * LPR + f4];
  float4 a = make_float4(diag * (float)xd.h[0], diag * (float)xd.h[1],
                         diag * (float)xd.h[2], diag * (float)xd.h[3]);
  int s = row_ptr[i], e = row_ptr[i + 1];

  for (int j0 = s; j0 < e; j0 += 16) {
    unsigned int pv[EPL];
#pragma unroll
    for (int u = 0; u < EPL; ++u) {
      int jj = j0 + f4 * EPL + u;
      pv[u] = cw[jj < e ? jj : (e - 1)];
    }
    H4 xv[16];
    float ww[16];
#pragma unroll
    for (int u = 0; u < 16; ++u) {
      unsigned int pu = (unsigned int)__shfl((int)pv[u % EPL], grpbase + u / EPL, 64);
      bool valid = (j0 + u) < e;
      ww[u] = valid ? h2f_bits(pu) : 0.0f;
      int ad = valid ? (int)(pu >> 16) : i;
      xv[u].u = xin[(size_t)ad * LPR + f4];
    }
#pragma unroll
    for (int u = 0; u < 16; ++u) {
      a.x += ww[u] * (float)xv[u].h[0];
      a.y += ww[u] * (float)xv[u].h[1];
      a.z += ww[u] * (float)xv[u].h[2];
      a.w += ww[u] * (float)xv[u].h[3];
    }
  }

  float4 r;
  if (MODE == 1) {
    H4 sv;
    sv.u = sub[(size_t)i * LPR + f4];
    r = make_float4(2.0f * a.x - (float)sv.h[0], 2.0f * a.y - (float)sv.h[1],
                    2.0f * a.z - (float)sv.h[2], 2.0f * a.w - (float)sv.h[3]);
  } else {
    r = a;
  }
  H4 o;
  o.u.x = f2h_bits(r.x);
  o.u.y = f2h_bits(r.y);
  o.u.z = f2h_bits(r.z);
  o.u.w = f2h_bits(r.w);
  xout[(size_t)i * LPR + f4] = o.u;
}

// ---------------------------------------------------------------------------
// MFMA GEMM over slot-major slices: D[N x 64] = A_cat[N x KT*32] @ Wpk (+bias,
// relu -> fp16 slot0/1 of dst slices) or raw fp32 acc (LAST).
// A slice layout: SW=32: K-tile kt == slot kt, lane k-off=(l>>4)*8.
//                 SW=16: kt spans slots {2kt,2kt+1}: slot=2kt+((l>>4)>>1),
//                 off=((l>>4)&1)*8.
// ---------------------------------------------------------------------------
template <int SW, int KT, bool LAST>
__global__ __launch_bounds__(256) void gemm_mfma(const ushort* __restrict__ A,
                                                 const ushort* __restrict__ Wpk,
                                                 const float* __restrict__ bias,
                                                 ushort* __restrict__ dsth,
                                                 float* __restrict__ dacc, int n) {
  int l = threadIdx.x & 63;
  int tile = blockIdx.x * 4 + (threadIdx.x >> 6);
  int r0 = tile * 16;
  if (r0 >= n) return;
  size_t slotsz = (size_t)n * SW;
  int row = r0 + (l & 15);
  const f16x8* bp = (const f16x8*)Wpk + l;
  f32x4 c[4] = {{0.f, 0.f, 0.f, 0.f},
                {0.f, 0.f, 0.f, 0.f},
                {0.f, 0.f, 0.f, 0.f},
                {0.f, 0.f, 0.f, 0.f}};
#pragma unroll
  for (int kt = 0; kt < KT; ++kt) {
    int slot, off;
    if constexpr (SW == 32) {
      slot = kt;
      off = (l >> 4) << 3;
    } else {
      slot = 2 * kt + ((l >> 4) >> 1);
      off = ((l >> 4) & 1) << 3;
    }
    f16x8 af = *(const f16x8*)(A + slot * slotsz + (size_t)row * SW + off);
#pragma unroll
    for (int nt = 0; nt < 4; ++nt) {
      f16x8 bf = bp[(kt * 4 + nt) * 64];
      c[nt] = __builtin_amdgcn_mfma_f32_16x16x32_f16(af, bf, c[nt], 0, 0, 0);
    }
  }
  int rb = r0 + ((l >> 4) << 2);
  int cc = l & 15;
  size_t dslot = (size_t)n * 32;
#pragma unroll
  for (int nt = 0; nt < 4; ++nt) {
    int col = nt * 16 + cc;
    if (LAST) {
#pragma unroll
      for (int j = 0; j < 4; ++j) dacc[(size_t)(rb + j) * 64 + col] = c[nt][j];
    } else {
      float bv = bias[col];
      ushort* dbase = dsth + (col >> 5) * dslot + (col & 31);
#pragma unroll
      for (int j = 0; j < 4; ++j) {
        float v = fmaxf(c[nt][j] + bv, 0.0f);
        dbase[(size_t)(rb + j) * 32] = f2h_bits(v);
      }
    }
  }
}

// layer-3 epilogue: out[i] = sum_h relu(acc[i,h]+b[h]) * Wfc[h] + bfc
__global__ __launch_bounds__(256) void fc_fused_kernel(const float* __restrict__ acc,
                                                       const float* __restrict__ b,
                                                       const float* __restrict__ Wfc,
                                                       const float* __restrict__ bfc,
                                                       float* __restrict__ out, int n) {
  int i = blockIdx.x * 4 + threadIdx.y;
  if (i >= n) return;
  int l = threadIdx.x;
  float v = fmaxf(acc[(size_t)i * 64 + l] + b[l], 0.0f) * Wfc[l];
#pragma unroll
  for (int off = 32; off > 0; off >>= 1) v += __shfl_down(v, off, 64);
  if (l == 0) out[i] = v + bfc[0];
}

extern "C" void kernel_launch(void* const* d_in, const int* in_sizes, int n_in, void* d_out,
                              int out_size, void* d_ws, size_t ws_size, hipStream_t stream) {
  const float* x = (const float*)d_in[0];
  const int* ei = (const int*)d_in[1];
  const float* lamp = (const float*)d_in[2];
  const float* W1 = (const float*)d_in[3];
  const float* b1 = (const float*)d_in[4];
  const float* W2 = (const float*)d_in[5];
  const float* b2 = (const float*)d_in[6];
  const float* W3 = (const float*)d_in[7];
  const float* b3 = (const float*)d_in[8];
  const float* Wfc = (const float*)d_in[9];
  const float* bfc = (const float*)d_in[10];

  const int N = in_sizes[0] / 16;  // 50000 (< 65536 required for packing)
  const int E = in_sizes[1] / 2;
  const int* row = ei;
  const int* col = ei + E;

  // ---- workspace carve ----
  char* p = (char*)d_ws;
  auto alloc = [&](size_t bytes) {
    char* r = p;
    p += WS_ALIGN(bytes);
    return r;
  };
  int* deg = (int*)alloc((size_t)N * 4);
  int* row_ptr = (int*)alloc((size_t)(N + 1) * 4);
  int* cursor = (int*)alloc((size_t)N * 4);
  unsigned int* cw = (unsigned int*)alloc((size_t)E * 4);
  float* dis = (float*)alloc((size_t)N * 4);
  int* bsum = (int*)alloc(256 * 4);
  ushort* T1 = (ushort*)alloc((size_t)8 * N * 16 * 2);    // 8 slots [N][16] (slot7 = pad)
  ushort* TXC = (ushort*)alloc((size_t)14 * N * 32 * 2);  // 14 slots [N][32]
  float* acc = (float*)alloc((size_t)N * 64 * 4);
  ushort* Wpk1 = (ushort*)alloc((size_t)4 * 256 * 8 * 2);
  ushort* Wpk2 = (ushort*)alloc((size_t)14 * 256 * 8 * 2);
  ushort* Wpk3 = (ushort*)alloc((size_t)14 * 256 * 8 * 2);
  (void)ws_size;
  (void)n_in;
  (void)out_size;

  // ---- CSR build (per-row cursors) ----
  (void)hipMemsetAsync(deg, 0, (size_t)N * 4, stream);
  hist_kernel<<<(E + 255) / 256, 256, 0, stream>>>(row, E, deg);
  int nb = (N + 1023) / 1024;
  scan_sum_kernel<<<nb, 256, 0, stream>>>(deg, bsum, N);
  scan_bsum_kernel<<<1, 64, 0, stream>>>(bsum, nb);
  scan_out_kernel<<<nb, 256, 0, stream>>>(deg, bsum, row_ptr, cursor, dis, N);
  scatter_kernel<<<(E + 255) / 256, 256, 0, stream>>>(row, col, E, cursor, dis, lamp, cw);

  // ---- weight packing + input conversion ----
  x_to_slots_kernel<<<(N * 8 + 255) / 256, 256, 0, stream>>>(x, T1, N);
  wpk_prep<112, 4><<<4, 256, 0, stream>>>(W1, Wpk1);
  wpk_prep<448, 14><<<14, 256, 0, stream>>>(W2, Wpk2);
  wpk_prep<448, 14><<<14, 256, 0, stream>>>(W3, Wpk3);

  // ---- layer 1 (slices = whole 16-wide rows, slots [N][16]) ----
  {
    int ssz4 = N * 4;  // ushort4 per slot
    auto S = [&](int k) { return (ushort4*)T1 + (size_t)k * ssz4; };
    dim3 bs(4, 64);
    int gs = (N + 63) / 64;
    spmv_slice<16, 0, 1><<<gs, bs, 0, stream>>>(row_ptr, cw, lamp, S(0), nullptr, S(1), ssz4,
                                                N);
    for (int k = 2; k < 7; ++k)
      spmv_slice<16, 1, 1><<<gs, bs, 0, stream>>>(row_ptr, cw, lamp, S(k - 1), S(k - 2), S(k),
                                                  ssz4, N);
    gemm_mfma<16, 4, false><<<(N / 16 + 3) / 4 + 1, 256, 0, stream>>>(T1, Wpk1, b1, TXC,
                                                                      nullptr, N);
  }

  // ---- layers 2,3 (two 32-wide slices per k, fused launch; slot = 2k+s) ----
  for (int layer = 2; layer <= 3; ++layer) {
    int ssz4 = N * 8;  // ushort4 per slot
    auto S = [&](int k) { return (ushort4*)TXC + (size_t)(2 * k) * ssz4; };
    dim3 bs(8, 32);
    int gs = 2 * ((N + 31) / 32);
    spmv_slice<32, 0, 2><<<gs, bs, 0, stream>>>(row_ptr, cw, lamp, S(0), nullptr, S(1), ssz4,
                                                N);
    for (int k = 2; k < 7; ++k)
      spmv_slice<32, 1, 2><<<gs, bs, 0, stream>>>(row_ptr, cw, lamp, S(k - 1), S(k - 2), S(k),
                                                  ssz4, N);
    if (layer == 2)
      gemm_mfma<32, 14, false><<<(N / 16 + 3) / 4 + 1, 256, 0, stream>>>(TXC, Wpk2, b2, TXC,
                                                                         nullptr, N);
    else
      gemm_mfma<32, 14, true><<<(N / 16 + 3) / 4 + 1, 256, 0, stream>>>(TXC, Wpk3, nullptr,
                                                                        nullptr, acc, N);
  }

  // ---- fused bias+relu+FC ----
  fc_fused_kernel<<<(N + 3) / 4, dim3(64, 4), 0, stream>>>(acc, b3, Wfc, bfc, (float*)d_out,
                                                           N);
}

// Round 9
// 399.995 us; speedup vs baseline: 1.7465x; 1.0654x over previous
//
#include <hip/hip_runtime.h>
#include <math.h>

// ---------------------------------------------------------------------------
// ChebNet: 3x ChebConv(S=7) + ReLU, then FC(64->1).
// N=50000 nodes, E=800000 edges, F_IN=16, H=64.
// R9: (1) XCD-cohort scatter: cohort = blockIdx&7 owns rows [c*N/8,(c+1)*N/8),
// scans the full edge list, writes only its contiguous cw region -> writes
// stay in one XCD's L2 (kills 17x write amp); correct regardless of the
// block->XCD mapping. (2) SpMV gathers widened to 16B/lane (uint4 = 8 fp16
// features): half the VMEM instructions + fma_mix-friendly FMAs.
// Feature-sliced [N][32] fp16 buffers, slice = blockIdx&1. MFMA GEMM as R8.
// ---------------------------------------------------------------------------

#define WS_ALIGN(x) (((size_t)(x) + 255) & ~(size_t)255)

using f16x8 = __attribute__((ext_vector_type(8))) _Float16;
using f32x4 = __attribute__((ext_vector_type(4))) float;

__device__ inline float h2f_bits(unsigned int b) {
  unsigned short s = (unsigned short)(b & 0xffffu);
  _Float16 h;
  __builtin_memcpy(&h, &s, 2);
  return (float)h;
}
__device__ inline unsigned short f2h_bits(float f) {
  _Float16 h = (_Float16)f;
  unsigned short s;
  __builtin_memcpy(&s, &h, 2);
  return s;
}
union H8 {
  uint4 q;
  _Float16 h[8];
  ushort us[8];
};

__global__ __launch_bounds__(256) void hist_kernel(const int* __restrict__ row, int E,
                                                   int* __restrict__ deg) {
  int i = blockIdx.x * 256 + threadIdx.x;
  if (i < E) atomicAdd(&deg[row[i]], 1);
}

// ---- hierarchical scan ----
__global__ __launch_bounds__(256) void scan_sum_kernel(const int* __restrict__ deg,
                                                       int* __restrict__ bsum, int n) {
  int base = blockIdx.x * 1024 + threadIdx.x;
  int v = 0;
#pragma unroll
  for (int u = 0; u < 4; ++u) {
    int i = base + u * 256;
    if (i < n) v += deg[i];
  }
#pragma unroll
  for (int off = 32; off > 0; off >>= 1) v += __shfl_down(v, off, 64);
  __shared__ int ws[4];
  int lane = threadIdx.x & 63, wave = threadIdx.x >> 6;
  if (lane == 0) ws[wave] = v;
  __syncthreads();
  if (threadIdx.x == 0) bsum[blockIdx.x] = ws[0] + ws[1] + ws[2] + ws[3];
}

__global__ __launch_bounds__(64) void scan_bsum_kernel(int* __restrict__ bsum, int nb) {
  int t = threadIdx.x;
  int v = (t < nb) ? bsum[t] : 0;
  int sc = v;
#pragma unroll
  for (int off = 1; off < 64; off <<= 1) {
    int tv = __shfl_up(sc, off, 64);
    if (t >= off) sc += tv;
  }
  if (t < nb) bsum[t] = sc - v;
}

__global__ __launch_bounds__(256) void scan_out_kernel(const int* __restrict__ deg,
                                                       const int* __restrict__ bsum,
                                                       int* __restrict__ row_ptr,
                                                       int* __restrict__ cursor,
                                                       float* __restrict__ dis, int n) {
  int base = blockIdx.x * 1024 + threadIdx.x * 4;
  int loc[4];
  int s = 0;
#pragma unroll
  for (int u = 0; u < 4; ++u) {
    int i = base + u;
    loc[u] = (i < n) ? deg[i] : 0;
    s += loc[u];
  }
  int lane = threadIdx.x & 63, wave = threadIdx.x >> 6;
  int sc = s;
#pragma unroll
  for (int off = 1; off < 64; off <<= 1) {
    int tv = __shfl_up(sc, off, 64);
    if (lane >= off) sc += tv;
  }
  __shared__ int wtot[4];
  if (lane == 63) wtot[wave] = sc;
  __syncthreads();
  int pre = sc - s + bsum[blockIdx.x];
  for (int w = 0; w < wave; ++w) pre += wtot[w];
  if (blockIdx.x == 0 && threadIdx.x == 0) row_ptr[0] = 0;
  int running = pre;
#pragma unroll
  for (int u = 0; u < 4; ++u) {
    int i = base + u;
    if (i < n) {
      cursor[i] = running;
      dis[i] = (loc[u] > 0) ? (1.0f / sqrtf((float)loc[u])) : 0.0f;
      running += loc[u];
      row_ptr[i + 1] = running;
    }
  }
}

// XCD-cohort scatter: cohort c = blockIdx&7 owns rows [c*n/8,(c+1)*n/8).
// Every cohort scans the full edge list; writes land in a contiguous ~E/8
// region of cw owned by (presumably) one XCD's L2. Correct for ANY
// block->XCD mapping.  cw entry = (col<<16)|fp16(w).  N < 65536.
__global__ __launch_bounds__(256) void scatter_x8(const int* __restrict__ row,
                                                  const int* __restrict__ col, int E,
                                                  int* __restrict__ cursor,
                                                  const float* __restrict__ dis,
                                                  const float* __restrict__ lamp,
                                                  unsigned int* __restrict__ cw, int n) {
  int c = blockIdx.x & 7;
  int j = blockIdx.x >> 3;
  int nj = gridDim.x >> 3;
  int lo = (c * n) >> 3;
  int hi = ((c + 1) * n) >> 3;
  float sc = -(2.0f / lamp[0]);
  for (int i = j * 256 + threadIdx.x; i < E; i += nj * 256) {
    int r = row[i];
    if (r < lo || r >= hi) continue;
    int cc = col[i];
    int pos = atomicAdd(&cursor[r], 1);
    float w = sc * dis[r] * dis[cc];
    cw[pos] = ((unsigned int)cc << 16) | (unsigned int)f2h_bits(w);
  }
}

// x (N x 16 fp32) -> T1 slot0 fp16 dense [N][16]; zero pad slot 7.
__global__ __launch_bounds__(256) void x_to_slots_kernel(const float* __restrict__ x,
                                                         ushort* __restrict__ T1, int n) {
  int t = blockIdx.x * 256 + threadIdx.x;
  if (t < n * 4) {
    int row = t >> 2, q = t & 3;
    float4 v = ((const float4*)x)[(size_t)row * 4 + q];
    ushort4 o;
    o.x = f2h_bits(v.x);
    o.y = f2h_bits(v.y);
    o.z = f2h_bits(v.z);
    o.w = f2h_bits(v.w);
    ((ushort4*)T1)[(size_t)row * 4 + q] = o;
  } else if (t < n * 8) {
    int t2 = t - n * 4;
    ((ushort4*)(T1 + (size_t)7 * n * 16))[t2] = make_ushort4(0, 0, 0, 0);
  }
}

// Pack W ([KREAL][64] f32, zero-padded to KT*32) into MFMA B-fragment order.
template <int KREAL, int KT>
__global__ __launch_bounds__(256) void wpk_prep(const float* __restrict__ W,
                                                ushort* __restrict__ Wpk) {
  int t = blockIdx.x * 256 + threadIdx.x;
  if (t >= KT * 256) return;
  int kt = t >> 8, nt = (t >> 6) & 3, l = t & 63;
  int col = nt * 16 + (l & 15);
  int kb = kt * 32 + ((l >> 4) << 3);
  ushort tmp[8];
#pragma unroll
  for (int j = 0; j < 8; ++j) {
    int k = kb + j;
    float v = (k < KREAL) ? W[(size_t)k * 64 + col] : 0.0f;
    tmp[j] = f2h_bits(v);
  }
  ushort4* dst = (ushort4*)Wpk + (size_t)((kt * 4 + nt) * 64 + l) * 2;
  dst[0] = make_ushort4(tmp[0], tmp[1], tmp[2], tmp[3]);
  dst[1] = make_ushort4(tmp[4], tmp[5], tmp[6], tmp[7]);
}

// ---------------------------------------------------------------------------
// Feature-sliced SpMV, 16B (8 fp16) per lane.  MODE 0: out = spmv(xin);
// MODE 1: out = 2*spmv(xin) - sub.  SLICES=2: slice = blockIdx&1.
// ---------------------------------------------------------------------------
template <int SW, int MODE, int SLICES>
__global__ __launch_bounds__(256) void spmv_slice(const int* __restrict__ row_ptr,
                                                  const unsigned int* __restrict__ cw,
                                                  const float* __restrict__ lamp,
                                                  const ushort* __restrict__ xin,
                                                  const ushort* __restrict__ sub,
                                                  ushort* __restrict__ xout, int ssz,
                                                  int n) {
  constexpr int LPR = SW / 8;     // lanes per row (16B each)
  constexpr int RPB = 256 / LPR;  // rows per block
  constexpr int B = 8;            // edge batch depth
  constexpr int EPL = B / LPR;    // cw entries per lane per batch
  int bx = blockIdx.x;
  if (SLICES == 2) {
    int sl = bx & 1;
    bx >>= 1;
    xin += (size_t)sl * ssz;
    if (MODE == 1) sub += (size_t)sl * ssz;
    xout += (size_t)sl * ssz;
  }
  int i = bx * RPB + threadIdx.y;
  if (i >= n) return;
  int f8 = threadIdx.x;  // 0..LPR-1
  int lane = (threadIdx.y * LPR + f8) & 63;
  int grpbase = lane - f8;
  float diag = 2.0f / lamp[0] - 1.0f;
  H8 xd;
  xd.q = *(const uint4*)(xin + (size_t)i * SW + f8 * 8);
  float a[8];
#pragma unroll
  for (int j = 0; j < 8; ++j) a[j] = diag * (float)xd.h[j];
  int s = row_ptr[i], e = row_ptr[i + 1];

  for (int j0 = s; j0 < e; j0 += B) {
    unsigned int pv[EPL];
#pragma unroll
    for (int u = 0; u < EPL; ++u) {
      int jj = j0 + f8 * EPL + u;
      pv[u] = cw[jj < e ? jj : (e - 1)];
    }
    H8 xv[B];
    float ww[B];
#pragma unroll
    for (int u = 0; u < B; ++u) {
      unsigned int pu = (unsigned int)__shfl((int)pv[u % EPL], grpbase + u / EPL, 64);
      bool valid = (j0 + u) < e;
      ww[u] = valid ? h2f_bits(pu) : 0.0f;
      int ad = valid ? (int)(pu >> 16) : i;
      xv[u].q = *(const uint4*)(xin + (size_t)ad * SW + f8 * 8);
    }
#pragma unroll
    for (int u = 0; u < B; ++u)
#pragma unroll
      for (int j = 0; j < 8; ++j) a[j] += ww[u] * (float)xv[u].h[j];
  }

  float r[8];
  if (MODE == 1) {
    H8 sv;
    sv.q = *(const uint4*)(sub + (size_t)i * SW + f8 * 8);
#pragma unroll
    for (int j = 0; j < 8; ++j) r[j] = 2.0f * a[j] - (float)sv.h[j];
  } else {
#pragma unroll
    for (int j = 0; j < 8; ++j) r[j] = a[j];
  }
  H8 o;
#pragma unroll
  for (int j = 0; j < 8; ++j) o.us[j] = f2h_bits(r[j]);
  *(uint4*)(xout + (size_t)i * SW + f8 * 8) = o.q;
}

// ---------------------------------------------------------------------------
// MFMA GEMM over slot-major slices (as R8).
// ---------------------------------------------------------------------------
template <int SW, int KT, bool LAST>
__global__ __launch_bounds__(256) void gemm_mfma(const ushort* __restrict__ A,
                                                 const ushort* __restrict__ Wpk,
                                                 const float* __restrict__ bias,
                                                 ushort* __restrict__ dsth,
                                                 float* __restrict__ dacc, int n) {
  int l = threadIdx.x & 63;
  int tile = blockIdx.x * 4 + (threadIdx.x >> 6);
  int r0 = tile * 16;
  if (r0 >= n) return;
  size_t slotsz = (size_t)n * SW;
  int row = r0 + (l & 15);
  const f16x8* bp = (const f16x8*)Wpk + l;
  f32x4 c[4] = {{0.f, 0.f, 0.f, 0.f},
                {0.f, 0.f, 0.f, 0.f},
                {0.f, 0.f, 0.f, 0.f},
                {0.f, 0.f, 0.f, 0.f}};
#pragma unroll
  for (int kt = 0; kt < KT; ++kt) {
    int slot, off;
    if constexpr (SW == 32) {
      slot = kt;
      off = (l >> 4) << 3;
    } else {
      slot = 2 * kt + ((l >> 4) >> 1);
      off = ((l >> 4) & 1) << 3;
    }
    f16x8 af = *(const f16x8*)(A + slot * slotsz + (size_t)row * SW + off);
#pragma unroll
    for (int nt = 0; nt < 4; ++nt) {
      f16x8 bf = bp[(kt * 4 + nt) * 64];
      c[nt] = __builtin_amdgcn_mfma_f32_16x16x32_f16(af, bf, c[nt], 0, 0, 0);
    }
  }
  int rb = r0 + ((l >> 4) << 2);
  int cc = l & 15;
  size_t dslot = (size_t)n * 32;
#pragma unroll
  for (int nt = 0; nt < 4; ++nt) {
    int col = nt * 16 + cc;
    if (LAST) {
#pragma unroll
      for (int j = 0; j < 4; ++j) dacc[(size_t)(rb + j) * 64 + col] = c[nt][j];
    } else {
      float bv = bias[col];
      ushort* dbase = dsth + (col >> 5) * dslot + (col & 31);
#pragma unroll
      for (int j = 0; j < 4; ++j) {
        float v = fmaxf(c[nt][j] + bv, 0.0f);
        dbase[(size_t)(rb + j) * 32] = f2h_bits(v);
      }
    }
  }
}

// layer-3 epilogue: out[i] = sum_h relu(acc[i,h]+b[h]) * Wfc[h] + bfc
__global__ __launch_bounds__(256) void fc_fused_kernel(const float* __restrict__ acc,
                                                       const float* __restrict__ b,
                                                       const float* __restrict__ Wfc,
                                                       const float* __restrict__ bfc,
                                                       float* __restrict__ out, int n) {
  int i = blockIdx.x * 4 + threadIdx.y;
  if (i >= n) return;
  int l = threadIdx.x;
  float v = fmaxf(acc[(size_t)i * 64 + l] + b[l], 0.0f) * Wfc[l];
#pragma unroll
  for (int off = 32; off > 0; off >>= 1) v += __shfl_down(v, off, 64);
  if (l == 0) out[i] = v + bfc[0];
}

extern "C" void kernel_launch(void* const* d_in, const int* in_sizes, int n_in, void* d_out,
                              int out_size, void* d_ws, size_t ws_size, hipStream_t stream) {
  const float* x = (const float*)d_in[0];
  const int* ei = (const int*)d_in[1];
  const float* lamp = (const float*)d_in[2];
  const float* W1 = (const float*)d_in[3];
  const float* b1 = (const float*)d_in[4];
  const float* W2 = (const float*)d_in[5];
  const float* b2 = (const float*)d_in[6];
  const float* W3 = (const float*)d_in[7];
  const float* b3 = (const float*)d_in[8];
  const float* Wfc = (const float*)d_in[9];
  const float* bfc = (const float*)d_in[10];

  const int N = in_sizes[0] / 16;  // 50000 (< 65536 required for packing)
  const int E = in_sizes[1] / 2;
  const int* row = ei;
  const int* col = ei + E;

  // ---- workspace carve ----
  char* p = (char*)d_ws;
  auto alloc = [&](size_t bytes) {
    char* r = p;
    p += WS_ALIGN(bytes);
    return r;
  };
  int* deg = (int*)alloc((size_t)N * 4);
  int* row_ptr = (int*)alloc((size_t)(N + 1) * 4);
  int* cursor = (int*)alloc((size_t)N * 4);
  unsigned int* cw = (unsigned int*)alloc((size_t)E * 4);
  float* dis = (float*)alloc((size_t)N * 4);
  int* bsum = (int*)alloc(256 * 4);
  ushort* T1 = (ushort*)alloc((size_t)8 * N * 16 * 2);    // 8 slots [N][16] (slot7 = pad)
  ushort* TXC = (ushort*)alloc((size_t)14 * N * 32 * 2);  // 14 slots [N][32]
  float* acc = (float*)alloc((size_t)N * 64 * 4);
  ushort* Wpk1 = (ushort*)alloc((size_t)4 * 256 * 8 * 2);
  ushort* Wpk2 = (ushort*)alloc((size_t)14 * 256 * 8 * 2);
  ushort* Wpk3 = (ushort*)alloc((size_t)14 * 256 * 8 * 2);
  (void)ws_size;
  (void)n_in;
  (void)out_size;

  // ---- CSR build ----
  (void)hipMemsetAsync(deg, 0, (size_t)N * 4, stream);
  hist_kernel<<<(E + 255) / 256, 256, 0, stream>>>(row, E, deg);
  int nb = (N + 1023) / 1024;
  scan_sum_kernel<<<nb, 256, 0, stream>>>(deg, bsum, N);
  scan_bsum_kernel<<<1, 64, 0, stream>>>(bsum, nb);
  scan_out_kernel<<<nb, 256, 0, stream>>>(deg, bsum, row_ptr, cursor, dis, N);
  scatter_x8<<<2048, 256, 0, stream>>>(row, col, E, cursor, dis, lamp, cw, N);

  // ---- weight packing + input conversion ----
  x_to_slots_kernel<<<(N * 8 + 255) / 256, 256, 0, stream>>>(x, T1, N);
  wpk_prep<112, 4><<<4, 256, 0, stream>>>(W1, Wpk1);
  wpk_prep<448, 14><<<14, 256, 0, stream>>>(W2, Wpk2);
  wpk_prep<448, 14><<<14, 256, 0, stream>>>(W3, Wpk3);

  // ---- layer 1 (slots [N][16]; LPR=2, RPB=128) ----
  {
    int ssz = N * 16;  // ushorts per slot
    auto S = [&](int k) { return T1 + (size_t)k * ssz; };
    dim3 bs(2, 128);
    int gs = (N + 127) / 128;
    spmv_slice<16, 0, 1><<<gs, bs, 0, stream>>>(row_ptr, cw, lamp, S(0), nullptr, S(1), ssz,
                                                N);
    for (int k = 2; k < 7; ++k)
      spmv_slice<16, 1, 1><<<gs, bs, 0, stream>>>(row_ptr, cw, lamp, S(k - 1), S(k - 2), S(k),
                                                  ssz, N);
    gemm_mfma<16, 4, false><<<(N / 16 + 3) / 4 + 1, 256, 0, stream>>>(T1, Wpk1, b1, TXC,
                                                                      nullptr, N);
  }

  // ---- layers 2,3 (two 32-wide slices per k, fused; slot = 2k+s; LPR=4) ----
  for (int layer = 2; layer <= 3; ++layer) {
    int ssz = N * 32;  // ushorts per slot
    auto S = [&](int k) { return TXC + (size_t)(2 * k) * ssz; };
    dim3 bs(4, 64);
    int gs = 2 * ((N + 63) / 64);
    spmv_slice<32, 0, 2><<<gs, bs, 0, stream>>>(row_ptr, cw, lamp, S(0), nullptr, S(1), ssz,
                                                N);
    for (int k = 2; k < 7; ++k)
      spmv_slice<32, 1, 2><<<gs, bs, 0, stream>>>(row_ptr, cw, lamp, S(k - 1), S(k - 2), S(k),
                                                  ssz, N);
    if (layer == 2)
      gemm_mfma<32, 14, false><<<(N / 16 + 3) / 4 + 1, 256, 0, stream>>>(TXC, Wpk2, b2, TXC,
                                                                         nullptr, N);
    else
      gemm_mfma<32, 14, true><<<(N / 16 + 3) / 4 + 1, 256, 0, stream>>>(TXC, Wpk3, nullptr,
                                                                        nullptr, acc, N);
  }

  // ---- fused bias+relu+FC ----
  fc_fused_kernel<<<(N + 3) / 4, dim3(64, 4), 0, stream>>>(acc, b3, Wfc, bfc, (float*)d_out,
                                                           N);
}